// Round 17
// baseline (148.735 us; speedup 1.0000x reference)
//
#include <hip/hip_runtime.h>
#include <stdint.h>

// DILATE loss, B=32, L=512, DIM=16, gamma=1e-3, alpha=0.5.
//
// Round-17 = R16 (two batches per block; 2 waves/SIMD TLP) with the compile
// fix: asm base must be BLOCK-uniform for the "s" constraint -- use the
// kernel-arg pointer Dg and fold the per-half batch offset (b * 8MiB,
// wave-uniform, fits int32) into the 32-bit voffset after clamping.
// R16's "s"(Db) with Db = Dg + b*STRF2 (h-dependent) forced a VGPR base ->
// invalid operand for global_load saddr form.
//
//   kA : Dsk2[b][q][i*2+(j&1)], q = j/2 + i/2 (doubly-skewed, coalesced DP
//        loads: one dwordx4 per lane-step, 1024B contiguous per wave).
//   kP : 512 threads = 8 waves; waves 0-3 -> batch 2*blk, 4-7 -> 2*blk+1.
//        Per batch-half: lane tp owns rows {2tp,2tp+1}; step s processes
//        cols c0=2p,c1=2p+1, p=s-tp-16w (560 steps). 8 asm load slots,
//        counted s_waitcnt vmcnt(7). Cross-wave: 64-slot LDS ring,
//        barrier every 8 steps. T[i,j] = T[argmin parent] + (i-j)^2.
//   kC : combine -> scalar loss.
// Junk cells: clamped loads / 0xAA poison -> fmax(D,0)=0 ->
// R_junk = 1e10 exactly; inert (R13/R15-proven).
// Tie priority (all passing rounds): diag > up > left.

#define N 512
#define NB 32
#define BIGF 1e10f
#define QN 512
#define STRF2 ((size_t)QN * 1024)      // floats per batch (2 MiB)
#define VOMAX2 ((int)(STRF2 * 4 - 16))

typedef unsigned int u32;
typedef float f32x4 __attribute__((ext_vector_type(4)));
typedef float f32x2 __attribute__((ext_vector_type(2)));

__device__ __forceinline__ float dppshr(float x, float oldv) {
    // lane l gets lane l-1's x; lane 0 keeps oldv (bound_ctrl=false)
    return __int_as_float(__builtin_amdgcn_update_dpp(
        __float_as_int(oldv), __float_as_int(x), 0x138, 0xF, 0xF, false));
}

// ---------------- kA: pairwise squared distances -> doubly-skewed ----------
__global__ __launch_bounds__(512) void kA(const float* __restrict__ inp,
                                          const float* __restrict__ tgt,
                                          float* __restrict__ Dg) {
    const int b = blockIdx.y;
    const int jc = blockIdx.x;         // group of 4 columns
    const int tid = (int)threadIdx.x;  // row index i in [0,512)
    __shared__ float xs[4][16];        // x[j] = inp[b,j]-inp[b,0]
    if (tid < 64) {
        int c = tid >> 4, d = tid & 15;
        int j = jc * 4 + c;
        xs[c][d] = inp[(((size_t)b * N + j) << 4) + d] -
                   inp[(((size_t)b * N) << 4) + d];
    }
    __syncthreads();
    const float4* t4 = (const float4*)(tgt + (((size_t)b * N + tid) << 4));
    float4 ta = t4[0], tb = t4[1], tc = t4[2], td = t4[3];
    float s[4];
#pragma unroll
    for (int c = 0; c < 4; ++c) {
        float acc = 0.f, e;
        e = ta.x - xs[c][0];  acc = fmaf(e, e, acc);
        e = ta.y - xs[c][1];  acc = fmaf(e, e, acc);
        e = ta.z - xs[c][2];  acc = fmaf(e, e, acc);
        e = ta.w - xs[c][3];  acc = fmaf(e, e, acc);
        e = tb.x - xs[c][4];  acc = fmaf(e, e, acc);
        e = tb.y - xs[c][5];  acc = fmaf(e, e, acc);
        e = tb.z - xs[c][6];  acc = fmaf(e, e, acc);
        e = tb.w - xs[c][7];  acc = fmaf(e, e, acc);
        e = tc.x - xs[c][8];  acc = fmaf(e, e, acc);
        e = tc.y - xs[c][9];  acc = fmaf(e, e, acc);
        e = tc.z - xs[c][10]; acc = fmaf(e, e, acc);
        e = tc.w - xs[c][11]; acc = fmaf(e, e, acc);
        e = td.x - xs[c][12]; acc = fmaf(e, e, acc);
        e = td.y - xs[c][13]; acc = fmaf(e, e, acc);
        e = td.z - xs[c][14]; acc = fmaf(e, e, acc);
        e = td.w - xs[c][15]; acc = fmaf(e, e, acc);
        s[c] = acc;
    }
    // write two float2s: col-pairs (jc*4, +1) and (jc*4+2, +3)
    float* outB = Dg + (size_t)b * STRF2;
    const int q0 = jc * 2 + (tid >> 1);
    f32x2 w0; w0.x = s[0]; w0.y = s[1];
    f32x2 w1; w1.x = s[2]; w1.y = s[3];
    *(f32x2*)(outB + (size_t)q0 * 1024 + tid * 2) = w0;
    *(f32x2*)(outB + (size_t)(q0 + 1) * 1024 + tid * 2) = w1;
}

// ---------------- kP: 2-batch x 4-wave skew-2 pipelined wavefront DP -------
__global__ __launch_bounds__(512) void kP(const float* __restrict__ Dg,
                                          float* __restrict__ acc) {
    const int tid = (int)threadIdx.x;
    const int h = tid >> 8;        // batch half within block
    const int tp = tid & 255;      // per-batch thread id
    const int w = tp >> 6, lam = tp & 63;
    const int b = blockIdx.x * 2 + h;
    // wave-uniform byte offset of this half's batch (fits int32: <= 250MiB)
    const int bOff = (int)((size_t)b * STRF2 * 4);

    __shared__ __align__(16) f32x2 ring[2][3][64];
    __shared__ __align__(16) f32x2 dump2[72];  // shared by both halves

    for (int i = tid; i < 2 * 3 * 64 + 72; i += 512) {
        f32x2 z; z.x = BIGF; z.y = 0.f;
        ((f32x2*)ring)[i] = z;
    }
    __syncthreads();

    // 8 load slots; slot k covers steps s == k (mod 8).
    // batch-relative voffset = (s - 16w)*4096 + tp*16, clamped at issue,
    // then + bOff (uniform shift into batch b) against block-uniform Dg.
    int vo0, vo1, vo2, vo3, vo4, vo5, vo6, vo7;
    f32x4 d0, d1, d2, d3, d4, d5, d6, d7;
    {
        const int vb = tp * 16 - 16 * w * 4096;
        vo0 = vb;            vo1 = vb + 4096;     vo2 = vb + 2 * 4096;
        vo3 = vb + 3 * 4096; vo4 = vb + 4 * 4096; vo5 = vb + 5 * 4096;
        vo6 = vb + 6 * 4096; vo7 = vb + 7 * 4096;
    }

#define LOAD(k)                                                               \
    do {                                                                      \
        int va_ = min(max(vo##k, 0), VOMAX2) + bOff;                          \
        asm volatile("global_load_dwordx4 %0, %1, %2"                         \
                     : "=v"(d##k) : "v"(va_), "s"(Dg));                       \
    } while (0)

    LOAD(0); LOAD(1); LOAD(2); LOAD(3); LOAD(4); LOAD(5); LOAD(6); LOAD(7);

    // DP state (R15 semantics verbatim, tp in place of tid)
    float L0R = BIGF, L1R = BIGF, L0T = 0.f, L1T = 0.f;  // own cols at c1
    float hA = BIGF, hB = BIGF, hAT = 0.f, hBT = 0.f;    // dpp handoffs
    float sBold = (tp == 0) ? 0.f : BIGF, sBoldT = 0.f;  // diag for (r0,c0)
    float dr = (float)(4 * tp + 32 * w);                 // (i-j) at (r0,c0)
    int pp = -(tp + 16 * w);                             // pair index
    float Rfin = 0.f, Tfin = 0.f;

    const bool is_cons = (lam == 0) && (w > 0);
    f32x2* base2 = ((lam == 63) && (w < 3)) ? &ring[h][w][0] : &dump2[0];
    const f32x2* ringR = (w > 0) ? &ring[h][w - 1][0] : &ring[h][0][0];
    int rb = (-160 * w) & 63;

    f32x4 bkA[4], bkB[4];

#define READBANK(X)                                                           \
    do {                                                                      \
        if (is_cons) {                                                        \
            X[0] = *(const f32x4*)(ringR + (rb & 63));                        \
            X[1] = *(const f32x4*)(ringR + ((rb + 2) & 63));                  \
            X[2] = *(const f32x4*)(ringR + ((rb + 4) & 63));                  \
            X[3] = *(const f32x4*)(ringR + ((rb + 6) & 63));                  \
        }                                                                     \
        rb = (rb + 8) & 63;                                                   \
    } while (0)

    READBANK(bkA);  // prime: handoff data for steps 0..3

    // d layout: d.x=D(r0,c0) d.y=D(r0,c1) d.z=D(r1,c0) d.w=D(r1,c1)
#define STEP(k, BX, j)                                                        \
    do {                                                                      \
        asm volatile("s_waitcnt vmcnt(7)" : "+v"(d##k));                      \
        float D00 = fmaxf(d##k.x, 0.f), D01 = fmaxf(d##k.y, 0.f);             \
        float D10 = fmaxf(d##k.z, 0.f), D11 = fmaxf(d##k.w, 0.f);             \
        float upA = is_cons ? BX[j].x : hA;                                   \
        float utA = is_cons ? BX[j].y : hAT;                                  \
        float upB = is_cons ? BX[j].z : hB;                                   \
        float utB = is_cons ? BX[j].w : hBT;                                  \
        /* (r0,c0): up=upA dg=sBold lf=L0 */                                  \
        float mn0 = fminf(upA, fminf(sBold, L0R));                            \
        float Ts0 = (mn0 == sBold) ? sBoldT : ((mn0 == upA) ? utA : L0T);     \
        float R00 = D00 + mn0;                                                \
        float T00 = fmaf(dr, dr, Ts0);                                        \
        /* (r1,c0): up=R00 dg=L0 lf=L1 */                                     \
        float mn1 = fminf(R00, fminf(L0R, L1R));                              \
        float Ts1 = (mn1 == L0R) ? L0T : ((mn1 == R00) ? T00 : L1T);          \
        float drp = dr + 1.f;                                                 \
        float R10 = D10 + mn1;                                                \
        float T10 = fmaf(drp, drp, Ts1);                                      \
        /* (r0,c1): up=upB dg=upA lf=R00 */                                   \
        float mn2 = fminf(upB, fminf(upA, R00));                              \
        float Ts2 = (mn2 == upA) ? utA : ((mn2 == upB) ? utB : T00);          \
        float drm = dr - 1.f;                                                 \
        float R01 = D01 + mn2;                                                \
        float T01 = fmaf(drm, drm, Ts2);                                      \
        /* (r1,c1): up=R01 dg=R00 lf=R10 */                                   \
        float mn3 = fminf(R01, fminf(R00, R10));                              \
        float Ts3 = (mn3 == R00) ? T00 : ((mn3 == R01) ? T01 : T10);          \
        float R11v = D11 + mn3;                                               \
        float T11v = fmaf(dr, dr, Ts3);                                       \
        bool hit = (pp == 255);                                               \
        Rfin = hit ? R11v : Rfin;                                             \
        Tfin = hit ? T11v : Tfin;                                             \
        {                                                                     \
            int c0_ = 2 * pp;                                                 \
            f32x4 wv; wv.x = R10; wv.y = T10; wv.z = R11v; wv.w = T11v;       \
            *(f32x4*)(base2 + (c0_ & 63)) = wv;                               \
        }                                                                     \
        L0R = R01; L0T = T01; L1R = R11v; L1T = T11v;                         \
        sBold = upB; sBoldT = utB;                                            \
        hA = dppshr(R10, BIGF); hAT = dppshr(T10, 0.f);                       \
        hB = dppshr(R11v, BIGF); hBT = dppshr(T11v, 0.f);                     \
        dr -= 2.f; pp += 1;                                                   \
        vo##k += 32768; /* +8 q-blocks for this slot's next use */            \
        LOAD(k);                                                              \
    } while (0)

    for (int n = 0; n < 70; ++n) {  // 560 steps; tp 255 capture at s=558
        asm volatile("s_waitcnt lgkmcnt(0)" ::: "memory");
        __builtin_amdgcn_s_barrier();
        READBANK(bkB);  // handoff data for steps 8n+4..8n+7
        STEP(0, bkA, 0); STEP(1, bkA, 1); STEP(2, bkA, 2); STEP(3, bkA, 3);
        READBANK(bkA);  // handoff data for steps 8(n+1)..8(n+1)+3
        STEP(4, bkB, 0); STEP(5, bkB, 1); STEP(6, bkB, 2); STEP(7, bkB, 3);
    }
#undef STEP
#undef READBANK
#undef LOAD

    asm volatile("s_waitcnt vmcnt(0)" ::: "memory");  // drain before exit
    if (tp == 255) {
        acc[b] = Rfin;       // hard-DTW value Rp[N,N]
        acc[NB + b] = Tfin;  // sum (i-j)^2 along argmin path
    }
}

// ---------------- kC: combine over batches ---------------------------------
__global__ void kC(const float* __restrict__ acc, float* __restrict__ out) {
    const int l = (int)threadIdx.x;
    float vs = (l < NB) ? acc[l] : 0.f;
    float vt = (l < NB) ? acc[NB + l] : 0.f;
#pragma unroll
    for (int o = 32; o >= 1; o >>= 1) {
        vs += __shfl_down(vs, o);
        vt += __shfl_down(vt, o);
    }
    if (l == 0)
        out[0] = 0.5f * (vs / (float)NB) +
                 0.5f * (vt / ((float)NB * (float)(N * N)));
}

__global__ void kSentinel(float* out) { out[0] = -12345.0f; }

extern "C" void kernel_launch(void* const* d_in, const int* in_sizes, int n_in,
                              void* d_out, int out_size, void* d_ws, size_t ws_size,
                              hipStream_t stream) {
    const float* inp = (const float*)d_in[0];
    const float* tgt = (const float*)d_in[1];
    float* out = (float*)d_out;

    const size_t DSZ = (size_t)NB * STRF2 * sizeof(float);  // 64 MiB
    const size_t NEEDED = 256 + DSZ;
    if (ws_size < NEEDED) {
        kSentinel<<<1, 1, 0, stream>>>(out);
        return;
    }
    char* ws = (char*)d_ws;
    float* acc = (float*)ws;  // [0..31] shape, [32..63] temporal
    float* Dg = (float*)(ws + 256);

    kA<<<dim3(N / 4, NB), 512, 0, stream>>>(inp, tgt, Dg);
    kP<<<NB / 2, 512, 0, stream>>>(Dg, acc);
    kC<<<1, 64, 0, stream>>>(acc, out);
}

// Round 18
// 120.290 us; speedup vs baseline: 1.2365x; 1.2365x over previous
//
#include <hip/hip_runtime.h>
#include <stdint.h>

// DILATE loss, B=32, L=512, DIM=16, gamma=1e-3, alpha=0.5.
//
// Round-18 = R15 (best kP structure, absmax 0.0) with two fixes:
//  (1) kP: bkA/bkB ring banks (32 VGPRs) -> 2-reg ping-pong ds_read, 2 steps
//      ahead. R15/R17 showed VGPR_Count=48 < the 64+ needed -> banks spilled
//      to SCRATCH; scratch ops are VMEM -> extra ~50 instr/step AND they
//      pollute the counted vmcnt(7) pipeline. Ping-pong removes the spill.
//  (2) kA: iterate DIAGONALLY (block owns a q-chunk) so stores are fully
//      coalesced f32x2 at q*1024 + 2*tid (old kA scattered 8B chunks at
//      4KB stride -> ~22us store-line-bound).
//
//   Dsk2[b][q][i*2+(j&1)], q = j/2 + i/2: kP lane tp reads its 4 cells
//   (rows 2tp,2tp+1 x cols 2p,2p+1) as ONE dwordx4 at q*4096 + tp*16.
//   kP: 32 blocks x 256 thr (4 waves); 560 steps; 8 asm load slots with
//   counted s_waitcnt vmcnt(7); DPP within-wave handoff; 64-slot LDS ring
//   + barrier every 8 steps across waves. T[i,j]=T[argmin par]+(i-j)^2.
// Junk cells: clamped loads / poison -> fmax(D,0)=0 -> R_junk = 1e10
// exactly; inert (R13/R15-proven). Tie priority: diag > up > left.

#define N 512
#define NB 32
#define BIGF 1e10f
#define QN 512
#define STRF2 ((size_t)QN * 1024)      // floats per batch (2 MiB)
#define VOMAX2 ((int)(STRF2 * 4 - 16))

typedef unsigned int u32;
typedef float f32x4 __attribute__((ext_vector_type(4)));
typedef float f32x2 __attribute__((ext_vector_type(2)));

__device__ __forceinline__ float dppshr(float x, float oldv) {
    // lane l gets lane l-1's x; lane 0 keeps oldv (bound_ctrl=false)
    return __int_as_float(__builtin_amdgcn_update_dpp(
        __float_as_int(oldv), __float_as_int(x), 0x138, 0xF, 0xF, false));
}

// ---------------- kA: diagonal iteration, coalesced stores -----------------
__global__ __launch_bounds__(512) void kA(const float* __restrict__ inp,
                                          const float* __restrict__ tgt,
                                          float* __restrict__ Dg) {
    const int b = blockIdx.y;
    const int qbase = blockIdx.x * 64;  // q-chunk
    const int tid = (int)threadIdx.x;   // row index i in [0,512)
    __shared__ float xls[512 * 20];     // x[j], pitch 20 floats (16B-aligned)

    {   // stage x[j] = inp[b,j] - inp[b,0]
        const float4* ip = (const float4*)(inp + (((size_t)b * N + tid) << 4));
        const float4* op = (const float4*)(inp + (((size_t)b * N) << 4));
        float4 v0 = ip[0], v1 = ip[1], v2 = ip[2], v3 = ip[3];
        float4 o0 = op[0], o1 = op[1], o2 = op[2], o3 = op[3];
        v0.x -= o0.x; v0.y -= o0.y; v0.z -= o0.z; v0.w -= o0.w;
        v1.x -= o1.x; v1.y -= o1.y; v1.z -= o1.z; v1.w -= o1.w;
        v2.x -= o2.x; v2.y -= o2.y; v2.z -= o2.z; v2.w -= o2.w;
        v3.x -= o3.x; v3.y -= o3.y; v3.z -= o3.z; v3.w -= o3.w;
        float* xr = xls + tid * 20;
        ((float4*)xr)[0] = v0; ((float4*)(xr + 4))[0] = v1;
        ((float4*)(xr + 8))[0] = v2; ((float4*)(xr + 12))[0] = v3;
    }
    __syncthreads();

    // tgt row i=tid in registers
    const float4* t4 = (const float4*)(tgt + (((size_t)b * N + tid) << 4));
    float4 ta = t4[0], tb = t4[1], tc = t4[2], td = t4[3];
    float* outB = Dg + (size_t)b * STRF2;

    for (int qi = 0; qi < 64; ++qi) {
        const int q = qbase + qi;
        const int g = q - (tid >> 1);
        const bool valid = (unsigned)g <= 255u;
        const int j = min(max(g, 0), 255) * 2;
        const float* xr = xls + j * 20;        // x[j]
        const float* xs = xr + 20;             // x[j+1]
        float4 xa = ((const float4*)xr)[0], xb = ((const float4*)(xr + 4))[0];
        float4 xc = ((const float4*)(xr + 8))[0], xd = ((const float4*)(xr + 12))[0];
        float4 ya = ((const float4*)xs)[0], yb = ((const float4*)(xs + 4))[0];
        float4 yc = ((const float4*)(xs + 8))[0], yd = ((const float4*)(xs + 12))[0];
        float sA = 0.f, sB = 0.f, e;
        e = ta.x - xa.x; sA = fmaf(e, e, sA);  e = ta.x - ya.x; sB = fmaf(e, e, sB);
        e = ta.y - xa.y; sA = fmaf(e, e, sA);  e = ta.y - ya.y; sB = fmaf(e, e, sB);
        e = ta.z - xa.z; sA = fmaf(e, e, sA);  e = ta.z - ya.z; sB = fmaf(e, e, sB);
        e = ta.w - xa.w; sA = fmaf(e, e, sA);  e = ta.w - ya.w; sB = fmaf(e, e, sB);
        e = tb.x - xb.x; sA = fmaf(e, e, sA);  e = tb.x - yb.x; sB = fmaf(e, e, sB);
        e = tb.y - xb.y; sA = fmaf(e, e, sA);  e = tb.y - yb.y; sB = fmaf(e, e, sB);
        e = tb.z - xb.z; sA = fmaf(e, e, sA);  e = tb.z - yb.z; sB = fmaf(e, e, sB);
        e = tb.w - xb.w; sA = fmaf(e, e, sA);  e = tb.w - yb.w; sB = fmaf(e, e, sB);
        e = tc.x - xc.x; sA = fmaf(e, e, sA);  e = tc.x - yc.x; sB = fmaf(e, e, sB);
        e = tc.y - xc.y; sA = fmaf(e, e, sA);  e = tc.y - yc.y; sB = fmaf(e, e, sB);
        e = tc.z - xc.z; sA = fmaf(e, e, sA);  e = tc.z - yc.z; sB = fmaf(e, e, sB);
        e = tc.w - xc.w; sA = fmaf(e, e, sA);  e = tc.w - yc.w; sB = fmaf(e, e, sB);
        e = td.x - xd.x; sA = fmaf(e, e, sA);  e = td.x - yd.x; sB = fmaf(e, e, sB);
        e = td.y - xd.y; sA = fmaf(e, e, sA);  e = td.y - yd.y; sB = fmaf(e, e, sB);
        e = td.z - xd.z; sA = fmaf(e, e, sA);  e = td.z - yd.z; sB = fmaf(e, e, sB);
        e = td.w - xd.w; sA = fmaf(e, e, sA);  e = td.w - yd.w; sB = fmaf(e, e, sB);
        if (valid) {
            f32x2 wv; wv.x = sA; wv.y = sB;
            *(f32x2*)(outB + (size_t)q * 1024 + tid * 2) = wv;
        }
    }
}

// ---------------- kP: 4-wave skew-2 pipelined wavefront DP -----------------
__global__ __launch_bounds__(256) void kP(const float* __restrict__ Dg,
                                          float* __restrict__ acc) {
    const int b = blockIdx.x;
    const int tid = (int)threadIdx.x;
    const int w = tid >> 6, lam = tid & 63;
    const float* __restrict__ Db = Dg + (size_t)b * STRF2;

    __shared__ __align__(16) f32x2 ring[3][64];
    __shared__ __align__(16) f32x2 dump2[72];

    for (int i = tid; i < 3 * 64 + 72; i += 256) {
        f32x2 z; z.x = BIGF; z.y = 0.f;
        ((f32x2*)ring)[i] = z;
    }
    __syncthreads();

    // 8 load slots; slot k covers steps s == k (mod 8).
    // voffset = (s - 16w)*4096 + tid*16, clamped at issue.
    int vo0, vo1, vo2, vo3, vo4, vo5, vo6, vo7;
    f32x4 d0, d1, d2, d3, d4, d5, d6, d7;
    {
        const int vb = tid * 16 - 16 * w * 4096;
        vo0 = vb;            vo1 = vb + 4096;     vo2 = vb + 2 * 4096;
        vo3 = vb + 3 * 4096; vo4 = vb + 4 * 4096; vo5 = vb + 5 * 4096;
        vo6 = vb + 6 * 4096; vo7 = vb + 7 * 4096;
    }

#define LOAD(k)                                                               \
    do {                                                                      \
        int va_ = min(max(vo##k, 0), VOMAX2);                                 \
        asm volatile("global_load_dwordx4 %0, %1, %2"                         \
                     : "=v"(d##k) : "v"(va_), "s"(Db));                       \
    } while (0)

    LOAD(0); LOAD(1); LOAD(2); LOAD(3); LOAD(4); LOAD(5); LOAD(6); LOAD(7);

    // DP state (R15 semantics verbatim)
    float L0R = BIGF, L1R = BIGF, L0T = 0.f, L1T = 0.f;  // own cols at c1
    float hA = BIGF, hB = BIGF, hAT = 0.f, hBT = 0.f;    // dpp handoffs
    float sBold = (tid == 0) ? 0.f : BIGF, sBoldT = 0.f; // diag for (r0,c0)
    float dr = (float)(4 * tid + 32 * w);                // (i-j) at (r0,c0)
    int pp = -(tid + 16 * w);                            // pair index
    float Rfin = 0.f, Tfin = 0.f;

    const bool is_cons = (lam == 0) && (w > 0);
    f32x2* base2 = ((lam == 63) && (w < 3)) ? &ring[w][0] : &dump2[0];
    const f32x2* ringR = (w > 0) ? &ring[w - 1][0] : &ring[0][0];
    int rb = (-160 * w) & 63;

    // 2-deep ping-pong of ring entries (replaces spilled 32-VGPR banks):
    // pf0 serves even steps, pf1 odd steps; reloaded 2 steps ahead.
    f32x4 pf0, pf1;
    pf0.x = BIGF; pf0.y = 0.f; pf0.z = BIGF; pf0.w = 0.f;
    pf1 = pf0;
    if (is_cons) {
        pf0 = *(const f32x4*)(ringR + rb);
        pf1 = *(const f32x4*)(ringR + ((rb + 2) & 63));
    }
    rb = (rb + 4) & 63;

    // d layout: d.x=D(r0,c0) d.y=D(r0,c1) d.z=D(r1,c0) d.w=D(r1,c1)
#define STEP(k, PF)                                                           \
    do {                                                                      \
        asm volatile("s_waitcnt vmcnt(7)" : "+v"(d##k));                      \
        float D00 = fmaxf(d##k.x, 0.f), D01 = fmaxf(d##k.y, 0.f);             \
        float D10 = fmaxf(d##k.z, 0.f), D11 = fmaxf(d##k.w, 0.f);             \
        float upA = is_cons ? PF.x : hA;                                      \
        float utA = is_cons ? PF.y : hAT;                                     \
        float upB = is_cons ? PF.z : hB;                                      \
        float utB = is_cons ? PF.w : hBT;                                     \
        /* (r0,c0): up=upA dg=sBold lf=L0 */                                  \
        float mn0 = fminf(upA, fminf(sBold, L0R));                            \
        float Ts0 = (mn0 == sBold) ? sBoldT : ((mn0 == upA) ? utA : L0T);     \
        float R00 = D00 + mn0;                                                \
        float T00 = fmaf(dr, dr, Ts0);                                        \
        /* (r1,c0): up=R00 dg=L0 lf=L1 */                                     \
        float mn1 = fminf(R00, fminf(L0R, L1R));                              \
        float Ts1 = (mn1 == L0R) ? L0T : ((mn1 == R00) ? T00 : L1T);          \
        float drp = dr + 1.f;                                                 \
        float R10 = D10 + mn1;                                                \
        float T10 = fmaf(drp, drp, Ts1);                                      \
        /* (r0,c1): up=upB dg=upA lf=R00 */                                   \
        float mn2 = fminf(upB, fminf(upA, R00));                              \
        float Ts2 = (mn2 == upA) ? utA : ((mn2 == upB) ? utB : T00);          \
        float drm = dr - 1.f;                                                 \
        float R01 = D01 + mn2;                                                \
        float T01 = fmaf(drm, drm, Ts2);                                      \
        /* (r1,c1): up=R01 dg=R00 lf=R10 */                                   \
        float mn3 = fminf(R01, fminf(R00, R10));                              \
        float Ts3 = (mn3 == R00) ? T00 : ((mn3 == R01) ? T01 : T10);          \
        float R11v = D11 + mn3;                                               \
        float T11v = fmaf(dr, dr, Ts3);                                       \
        bool hit = (pp == 255);                                               \
        Rfin = hit ? R11v : Rfin;                                             \
        Tfin = hit ? T11v : Tfin;                                             \
        {                                                                     \
            int c0_ = 2 * pp;                                                 \
            f32x4 wv; wv.x = R10; wv.y = T10; wv.z = R11v; wv.w = T11v;       \
            *(f32x4*)(base2 + (c0_ & 63)) = wv;                               \
        }                                                                     \
        L0R = R01; L0T = T01; L1R = R11v; L1T = T11v;                         \
        sBold = upB; sBoldT = utB;                                            \
        hA = dppshr(R10, BIGF); hAT = dppshr(T10, 0.f);                       \
        hB = dppshr(R11v, BIGF); hBT = dppshr(T11v, 0.f);                     \
        if (is_cons) { PF = *(const f32x4*)(ringR + rb); }                    \
        rb = (rb + 2) & 63;                                                   \
        dr -= 2.f; pp += 1;                                                   \
        vo##k += 32768; /* +8 q-blocks for this slot's next use */            \
        LOAD(k);                                                              \
    } while (0)

    for (int n = 0; n < 70; ++n) {  // 560 steps; lane 255 capture at s=558
        asm volatile("s_waitcnt lgkmcnt(0)" ::: "memory");
        __builtin_amdgcn_s_barrier();
        STEP(0, pf0); STEP(1, pf1); STEP(2, pf0); STEP(3, pf1);
        STEP(4, pf0); STEP(5, pf1); STEP(6, pf0); STEP(7, pf1);
    }
#undef STEP
#undef LOAD

    asm volatile("s_waitcnt vmcnt(0)" ::: "memory");  // drain before exit
    if (tid == 255) {
        acc[b] = Rfin;       // hard-DTW value Rp[N,N]
        acc[NB + b] = Tfin;  // sum (i-j)^2 along argmin path
    }
}

// ---------------- kC: combine over batches ---------------------------------
__global__ void kC(const float* __restrict__ acc, float* __restrict__ out) {
    const int l = (int)threadIdx.x;
    float vs = (l < NB) ? acc[l] : 0.f;
    float vt = (l < NB) ? acc[NB + l] : 0.f;
#pragma unroll
    for (int o = 32; o >= 1; o >>= 1) {
        vs += __shfl_down(vs, o);
        vt += __shfl_down(vt, o);
    }
    if (l == 0)
        out[0] = 0.5f * (vs / (float)NB) +
                 0.5f * (vt / ((float)NB * (float)(N * N)));
}

__global__ void kSentinel(float* out) { out[0] = -12345.0f; }

extern "C" void kernel_launch(void* const* d_in, const int* in_sizes, int n_in,
                              void* d_out, int out_size, void* d_ws, size_t ws_size,
                              hipStream_t stream) {
    const float* inp = (const float*)d_in[0];
    const float* tgt = (const float*)d_in[1];
    float* out = (float*)d_out;

    const size_t DSZ = (size_t)NB * STRF2 * sizeof(float);  // 64 MiB
    const size_t NEEDED = 256 + DSZ;
    if (ws_size < NEEDED) {
        kSentinel<<<1, 1, 0, stream>>>(out);
        return;
    }
    char* ws = (char*)d_ws;
    float* acc = (float*)ws;  // [0..31] shape, [32..63] temporal
    float* Dg = (float*)(ws + 256);

    kA<<<dim3(8, NB), 512, 0, stream>>>(inp, tgt, Dg);
    kP<<<NB, 256, 0, stream>>>(Dg, acc);
    kC<<<1, 64, 0, stream>>>(acc, out);
}

// Round 19
// 105.777 us; speedup vs baseline: 1.4061x; 1.1372x over previous
//
#include <hip/hip_runtime.h>
#include <stdint.h>

// DILATE loss, B=32, L=512, DIM=16, gamma=1e-3, alpha=0.5.
//
// Round-19 = R15's kP VERBATIM (80.6us, absmax 0.0) + rebuilt kA:
//  - kA: block = (batch, 16-q group). x staged TRANSPOSED in LDS xt[d][j]
//    (reads: 16 ds_read_b64/cell-pair, lane-pairs stride 8B -> 2/bank = free;
//    R18's pitch-20 b128 reads were 4-8-way conflicted). Thread tid = row i;
//    per q stores f32x2 {D(i,j0),D(i,j0+1)} at q*1024+2*tid -> fully
//    coalesced (R15-kA scattered 8B per 64B line at 4KB stride -> ~23us).
//    Inactive threads don't store -> unwritten slots keep harness poison,
//    which kP's clamp+fmax(D,0) provably tolerates (R15 passed).
//  - kP: 32 blocks x 256 thr (4 waves), skew-2 wavefront, doubly-skewed
//    coalesced loads (one dwordx4/lane/step), 8 asm slots w/ counted
//    vmcnt(7), DPP in-wave handoff, 64-slot LDS ring + barrier per 8 steps.
//    T[i,j] = T[argmin parent] + (i-j)^2; tie priority diag > up > left.

#define N 512
#define NB 32
#define BIGF 1e10f
#define QN 512
#define STRF2 ((size_t)QN * 1024)      // floats per batch (2 MiB)
#define VOMAX2 ((int)(STRF2 * 4 - 16))

typedef unsigned int u32;
typedef float f32x4 __attribute__((ext_vector_type(4)));
typedef float f32x2 __attribute__((ext_vector_type(2)));

__device__ __forceinline__ float dppshr(float x, float oldv) {
    // lane l gets lane l-1's x; lane 0 keeps oldv (bound_ctrl=false)
    return __int_as_float(__builtin_amdgcn_update_dpp(
        __float_as_int(oldv), __float_as_int(x), 0x138, 0xF, 0xF, false));
}

// ---------------- kA: transposed-x LDS, coalesced stores -------------------
__global__ __launch_bounds__(512) void kA(const float* __restrict__ inp,
                                          const float* __restrict__ tgt,
                                          float* __restrict__ Dg) {
    const int b = blockIdx.y;
    const int qbase = blockIdx.x * 16;  // q-group
    const int tid = (int)threadIdx.x;   // row index i in [0,512)
    __shared__ float xt[16 * 512];      // x transposed: xt[d*512 + j]

    {   // stage x[j] = inp[b,j] - inp[b,0], transposed
        const float4* ip = (const float4*)(inp + (((size_t)b * N + tid) << 4));
        const float4* op = (const float4*)(inp + (((size_t)b * N) << 4));
        float4 v0 = ip[0], v1 = ip[1], v2 = ip[2], v3 = ip[3];
        float4 o0 = op[0], o1 = op[1], o2 = op[2], o3 = op[3];
        xt[0 * 512 + tid] = v0.x - o0.x;   xt[1 * 512 + tid] = v0.y - o0.y;
        xt[2 * 512 + tid] = v0.z - o0.z;   xt[3 * 512 + tid] = v0.w - o0.w;
        xt[4 * 512 + tid] = v1.x - o1.x;   xt[5 * 512 + tid] = v1.y - o1.y;
        xt[6 * 512 + tid] = v1.z - o1.z;   xt[7 * 512 + tid] = v1.w - o1.w;
        xt[8 * 512 + tid] = v2.x - o2.x;   xt[9 * 512 + tid] = v2.y - o2.y;
        xt[10 * 512 + tid] = v2.z - o2.z;  xt[11 * 512 + tid] = v2.w - o2.w;
        xt[12 * 512 + tid] = v3.x - o3.x;  xt[13 * 512 + tid] = v3.y - o3.y;
        xt[14 * 512 + tid] = v3.z - o3.z;  xt[15 * 512 + tid] = v3.w - o3.w;
    }
    __syncthreads();

    // tgt row i=tid in registers (compile-time indexed after unroll)
    const float4* t4 = (const float4*)(tgt + (((size_t)b * N + tid) << 4));
    float4 ta = t4[0], tb = t4[1], tc = t4[2], td = t4[3];
    const float tr[16] = {ta.x, ta.y, ta.z, ta.w, tb.x, tb.y, tb.z, tb.w,
                          tc.x, tc.y, tc.z, tc.w, td.x, td.y, td.z, td.w};
    float* outB = Dg + (size_t)b * STRF2;

#pragma unroll 4
    for (int qi = 0; qi < 16; ++qi) {
        const int q = qbase + qi;
        const int g = q - (tid >> 1);
        if ((unsigned)g > 255u) continue;  // inactive: whole-wave-contiguous
        const int j0 = 2 * g;
        float sA = 0.f, sB = 0.f;
#pragma unroll
        for (int d = 0; d < 16; ++d) {
            f32x2 xv = *(const f32x2*)(xt + d * 512 + j0);
            float e0 = tr[d] - xv.x; sA = fmaf(e0, e0, sA);
            float e1 = tr[d] - xv.y; sB = fmaf(e1, e1, sB);
        }
        f32x2 wv; wv.x = sA; wv.y = sB;
        *(f32x2*)(outB + (size_t)q * 1024 + tid * 2) = wv;
    }
}

// ---------------- kP: 4-wave skew-2 pipelined wavefront DP (R15 verbatim) --
__global__ __launch_bounds__(256) void kP(const float* __restrict__ Dg,
                                          float* __restrict__ acc) {
    const int b = blockIdx.x;
    const int tid = (int)threadIdx.x;
    const int w = tid >> 6, lam = tid & 63;
    const float* __restrict__ Db = Dg + (size_t)b * STRF2;

    __shared__ __align__(16) f32x2 ring[3][64];
    __shared__ __align__(16) f32x2 dump2[72];

    for (int i = tid; i < 3 * 64 + 72; i += 256) {
        f32x2 z; z.x = BIGF; z.y = 0.f;
        ((f32x2*)ring)[i] = z;
    }
    __syncthreads();

    // 8 load slots; slot k covers steps s == k (mod 8).
    // voffset = (s - 16w)*4096 + tid*16, clamped at issue.
    int vo0, vo1, vo2, vo3, vo4, vo5, vo6, vo7;
    f32x4 d0, d1, d2, d3, d4, d5, d6, d7;
    {
        const int vb = tid * 16 - 16 * w * 4096;
        vo0 = vb;            vo1 = vb + 4096;     vo2 = vb + 2 * 4096;
        vo3 = vb + 3 * 4096; vo4 = vb + 4 * 4096; vo5 = vb + 5 * 4096;
        vo6 = vb + 6 * 4096; vo7 = vb + 7 * 4096;
    }

#define LOAD(k)                                                               \
    do {                                                                      \
        int va_ = min(max(vo##k, 0), VOMAX2);                                 \
        asm volatile("global_load_dwordx4 %0, %1, %2"                         \
                     : "=v"(d##k) : "v"(va_), "s"(Db));                       \
    } while (0)

    LOAD(0); LOAD(1); LOAD(2); LOAD(3); LOAD(4); LOAD(5); LOAD(6); LOAD(7);

    // DP state
    float L0R = BIGF, L1R = BIGF, L0T = 0.f, L1T = 0.f;  // own cols at c1
    float hA = BIGF, hB = BIGF, hAT = 0.f, hBT = 0.f;    // dpp handoffs
    float sBold = (tid == 0) ? 0.f : BIGF, sBoldT = 0.f; // diag for (r0,c0)
    float dr = (float)(4 * tid + 32 * w);                // (i-j) at (r0,c0)
    int pp = -(tid + 16 * w);                            // pair index
    float Rfin = 0.f, Tfin = 0.f;

    const bool is_cons = (lam == 0) && (w > 0);
    f32x2* base2 = ((lam == 63) && (w < 3)) ? &ring[w][0] : &dump2[0];
    const f32x2* ringR = (w > 0) ? &ring[w - 1][0] : &ring[0][0];
    int rb = (-160 * w) & 63;

    f32x4 bkA[4], bkB[4];

#define READBANK(X)                                                           \
    do {                                                                      \
        if (is_cons) {                                                        \
            X[0] = *(const f32x4*)(ringR + (rb & 63));                        \
            X[1] = *(const f32x4*)(ringR + ((rb + 2) & 63));                  \
            X[2] = *(const f32x4*)(ringR + ((rb + 4) & 63));                  \
            X[3] = *(const f32x4*)(ringR + ((rb + 6) & 63));                  \
        }                                                                     \
        rb = (rb + 8) & 63;                                                   \
    } while (0)

    READBANK(bkA);  // prime: handoff data for steps 0..3

    // d layout: d.x=D(r0,c0) d.y=D(r0,c1) d.z=D(r1,c0) d.w=D(r1,c1)
#define STEP(k, BX, j)                                                        \
    do {                                                                      \
        asm volatile("s_waitcnt vmcnt(7)" : "+v"(d##k));                      \
        float D00 = fmaxf(d##k.x, 0.f), D01 = fmaxf(d##k.y, 0.f);             \
        float D10 = fmaxf(d##k.z, 0.f), D11 = fmaxf(d##k.w, 0.f);             \
        float upA = is_cons ? BX[j].x : hA;                                   \
        float utA = is_cons ? BX[j].y : hAT;                                  \
        float upB = is_cons ? BX[j].z : hB;                                   \
        float utB = is_cons ? BX[j].w : hBT;                                  \
        /* (r0,c0): up=upA dg=sBold lf=L0 */                                  \
        float mn0 = fminf(upA, fminf(sBold, L0R));                            \
        float Ts0 = (mn0 == sBold) ? sBoldT : ((mn0 == upA) ? utA : L0T);     \
        float R00 = D00 + mn0;                                                \
        float T00 = fmaf(dr, dr, Ts0);                                        \
        /* (r1,c0): up=R00 dg=L0 lf=L1 */                                     \
        float mn1 = fminf(R00, fminf(L0R, L1R));                              \
        float Ts1 = (mn1 == L0R) ? L0T : ((mn1 == R00) ? T00 : L1T);          \
        float drp = dr + 1.f;                                                 \
        float R10 = D10 + mn1;                                                \
        float T10 = fmaf(drp, drp, Ts1);                                      \
        /* (r0,c1): up=upB dg=upA lf=R00 */                                   \
        float mn2 = fminf(upB, fminf(upA, R00));                              \
        float Ts2 = (mn2 == upA) ? utA : ((mn2 == upB) ? utB : T00);          \
        float drm = dr - 1.f;                                                 \
        float R01 = D01 + mn2;                                                \
        float T01 = fmaf(drm, drm, Ts2);                                      \
        /* (r1,c1): up=R01 dg=R00 lf=R10 */                                   \
        float mn3 = fminf(R01, fminf(R00, R10));                              \
        float Ts3 = (mn3 == R00) ? T00 : ((mn3 == R01) ? T01 : T10);          \
        float R11v = D11 + mn3;                                               \
        float T11v = fmaf(dr, dr, Ts3);                                       \
        bool hit = (pp == 255);                                               \
        Rfin = hit ? R11v : Rfin;                                             \
        Tfin = hit ? T11v : Tfin;                                             \
        {                                                                     \
            int c0_ = 2 * pp;                                                 \
            f32x4 wv; wv.x = R10; wv.y = T10; wv.z = R11v; wv.w = T11v;       \
            *(f32x4*)(base2 + (c0_ & 63)) = wv;                               \
        }                                                                     \
        L0R = R01; L0T = T01; L1R = R11v; L1T = T11v;                         \
        sBold = upB; sBoldT = utB;                                            \
        hA = dppshr(R10, BIGF); hAT = dppshr(T10, 0.f);                       \
        hB = dppshr(R11v, BIGF); hBT = dppshr(T11v, 0.f);                     \
        dr -= 2.f; pp += 1;                                                   \
        vo##k += 32768; /* +8 q-blocks for this slot's next use */            \
        LOAD(k);                                                              \
    } while (0)

    for (int n = 0; n < 70; ++n) {  // 560 steps; lane 255 capture at s=558
        asm volatile("s_waitcnt lgkmcnt(0)" ::: "memory");
        __builtin_amdgcn_s_barrier();
        READBANK(bkB);  // handoff data for steps 8n+4..8n+7
        STEP(0, bkA, 0); STEP(1, bkA, 1); STEP(2, bkA, 2); STEP(3, bkA, 3);
        READBANK(bkA);  // handoff data for steps 8(n+1)..8(n+1)+3
        STEP(4, bkB, 0); STEP(5, bkB, 1); STEP(6, bkB, 2); STEP(7, bkB, 3);
    }
#undef STEP
#undef READBANK
#undef LOAD

    asm volatile("s_waitcnt vmcnt(0)" ::: "memory");  // drain before exit
    if (tid == 255) {
        acc[b] = Rfin;       // hard-DTW value Rp[N,N]
        acc[NB + b] = Tfin;  // sum (i-j)^2 along argmin path
    }
}

// ---------------- kC: combine over batches ---------------------------------
__global__ void kC(const float* __restrict__ acc, float* __restrict__ out) {
    const int l = (int)threadIdx.x;
    float vs = (l < NB) ? acc[l] : 0.f;
    float vt = (l < NB) ? acc[NB + l] : 0.f;
#pragma unroll
    for (int o = 32; o >= 1; o >>= 1) {
        vs += __shfl_down(vs, o);
        vt += __shfl_down(vt, o);
    }
    if (l == 0)
        out[0] = 0.5f * (vs / (float)NB) +
                 0.5f * (vt / ((float)NB * (float)(N * N)));
}

__global__ void kSentinel(float* out) { out[0] = -12345.0f; }

extern "C" void kernel_launch(void* const* d_in, const int* in_sizes, int n_in,
                              void* d_out, int out_size, void* d_ws, size_t ws_size,
                              hipStream_t stream) {
    const float* inp = (const float*)d_in[0];
    const float* tgt = (const float*)d_in[1];
    float* out = (float*)d_out;

    const size_t DSZ = (size_t)NB * STRF2 * sizeof(float);  // 64 MiB
    const size_t NEEDED = 256 + DSZ;
    if (ws_size < NEEDED) {
        kSentinel<<<1, 1, 0, stream>>>(out);
        return;
    }
    char* ws = (char*)d_ws;
    float* acc = (float*)ws;  // [0..31] shape, [32..63] temporal
    float* Dg = (float*)(ws + 256);

    kA<<<dim3(32, NB), 512, 0, stream>>>(inp, tgt, Dg);
    kP<<<NB, 256, 0, stream>>>(Dg, acc);
    kC<<<1, 64, 0, stream>>>(acc, out);
}